// Round 4
// baseline (31.323 us; speedup 1.0000x reference)
//
#include <hip/hip_runtime.h>
#include <hip/hip_bf16.h>

constexpr int S  = 256;
constexpr int D  = 768;
constexpr int KQ = 8;          // K slices
constexpr int KB = D / KQ;     // 96 per slice
constexpr int NT = KB / 16;    // 6 k-tiles of 16

// Stage 1: per-batch Gram slices G_kq = X[:, kq*96:(kq+1)*96] @ X^T slice, fp32.
// Grid (4, 8, 8): x = 64-col tile, y = batch, z = kq. 256 blocks, 256 threads.
// Per wave: lane l owns rows 4l..4l+3 (one ds_read_b128/kk from A[k][row]);
// wave w owns cols tJ+16w..+15 whose fragments are wave-uniform broadcast reads.
// Micro-tile 4x16 -> 64 FMA per (j,kk-quad) read. Fixed k order + fmaf symmetry
// makes every slice bitwise symmetric, so the C-tile is stored TRANSPOSED
// (perfectly coalesced float4 stores) and still equals the same matrix.
__global__ __launch_bounds__(256) void gram_kernel(const float* __restrict__ X,
                                                   float* __restrict__ G) {
    const int kq    = blockIdx.z;
    const int batch = blockIdx.y;
    const int tJ    = blockIdx.x * 64;
    const int kbase = kq * KB;
    const float* Xb = X + (size_t)batch * S * D;
    float* Gb = G + ((size_t)kq * 8 + batch) * S * S;

    __shared__ float As[16][260];   // [k][row], row-stride 1040 B (16B-aligned)
    __shared__ float Bs[64][16];    // [col][k]

    const int t = threadIdx.x;
    const int w = t >> 6;
    const int l = t & 63;

    const int srow  = t >> 2;        // 0..63 staging row group
    const int skoff = (t & 3) * 4;   // 0,4,8,12 staging k offset

    const float* pA = Xb + (size_t)srow * D + kbase + skoff;
    const float* pB = Xb + (size_t)(tJ + srow) * D + kbase + skoff;

    float4 acc[16];
#pragma unroll
    for (int j = 0; j < 16; ++j) acc[j] = make_float4(0.f, 0.f, 0.f, 0.f);

    // preload k-tile 0
    float4 rA0 = *(const float4*)(pA);
    float4 rA1 = *(const float4*)(pA + (size_t)64 * D);
    float4 rA2 = *(const float4*)(pA + (size_t)128 * D);
    float4 rA3 = *(const float4*)(pA + (size_t)192 * D);
    float4 rB  = *(const float4*)(pB);

    for (int kt = 0; kt < NT; ++kt) {
        __syncthreads();   // previous compute's LDS reads drained
        As[skoff+0][srow      ] = rA0.x; As[skoff+1][srow      ] = rA0.y;
        As[skoff+2][srow      ] = rA0.z; As[skoff+3][srow      ] = rA0.w;
        As[skoff+0][srow + 64 ] = rA1.x; As[skoff+1][srow + 64 ] = rA1.y;
        As[skoff+2][srow + 64 ] = rA1.z; As[skoff+3][srow + 64 ] = rA1.w;
        As[skoff+0][srow + 128] = rA2.x; As[skoff+1][srow + 128] = rA2.y;
        As[skoff+2][srow + 128] = rA2.z; As[skoff+3][srow + 128] = rA2.w;
        As[skoff+0][srow + 192] = rA3.x; As[skoff+1][srow + 192] = rA3.y;
        As[skoff+2][srow + 192] = rA3.z; As[skoff+3][srow + 192] = rA3.w;
        *(float4*)&Bs[srow][skoff] = rB;
        if (kt + 1 < NT) {             // prefetch next k-tile; lands under FMAs
            const int ko = (kt + 1) * 16;
            rA0 = *(const float4*)(pA + ko);
            rA1 = *(const float4*)(pA + (size_t)64 * D + ko);
            rA2 = *(const float4*)(pA + (size_t)128 * D + ko);
            rA3 = *(const float4*)(pA + (size_t)192 * D + ko);
            rB  = *(const float4*)(pB + ko);
        }
        __syncthreads();

        float4 af[16];
#pragma unroll
        for (int kk = 0; kk < 16; ++kk)
            af[kk] = *(const float4*)&As[kk][4 * l];

#pragma unroll
        for (int j = 0; j < 16; ++j) {
            const float4 b0 = *(const float4*)&Bs[w * 16 + j][0];
            const float4 b1 = *(const float4*)&Bs[w * 16 + j][4];
            const float4 b2 = *(const float4*)&Bs[w * 16 + j][8];
            const float4 b3 = *(const float4*)&Bs[w * 16 + j][12];
#define FMA4(AF, BV) \
            acc[j].x = fmaf((AF).x, (BV), acc[j].x); \
            acc[j].y = fmaf((AF).y, (BV), acc[j].y); \
            acc[j].z = fmaf((AF).z, (BV), acc[j].z); \
            acc[j].w = fmaf((AF).w, (BV), acc[j].w)
            FMA4(af[0],  b0.x); FMA4(af[1],  b0.y); FMA4(af[2],  b0.z); FMA4(af[3],  b0.w);
            FMA4(af[4],  b1.x); FMA4(af[5],  b1.y); FMA4(af[6],  b1.z); FMA4(af[7],  b1.w);
            FMA4(af[8],  b2.x); FMA4(af[9],  b2.y); FMA4(af[10], b2.z); FMA4(af[11], b2.w);
            FMA4(af[12], b3.x); FMA4(af[13], b3.y); FMA4(af[14], b3.z); FMA4(af[15], b3.w);
#undef FMA4
        }
    }

    // Transposed store (slice is bitwise symmetric): row tJ+16w+j, cols 4l..4l+3.
    float* gout = Gb + (size_t)(tJ + 16 * w) * S;
#pragma unroll
    for (int j = 0; j < 16; ++j)
        *(float4*)(gout + (size_t)j * S + 4 * l) = acc[j];
}

// Stage 2 (fused): wave handles position b = blockIdx.x*4 + wave:
//   P[b][:] = x_b @ W; w[b] = visibility of node b from node 0 (triangle reads).
__global__ __launch_bounds__(256) void visxw_kernel(const float* __restrict__ X,
                                                    const float* __restrict__ Wm,
                                                    const float* __restrict__ G,
                                                    float* __restrict__ P,
                                                    float* __restrict__ wv) {
    const int batch = blockIdx.y;
    const int wave  = threadIdx.x >> 6;
    const int lane  = threadIdx.x & 63;
    const int b     = blockIdx.x * 4 + wave;

    // ---- P[b][:] = x_b @ W ----
    const float* xs = X + ((size_t)batch * S + b) * D;
    float a0 = 0.f, a1 = 0.f, a2 = 0.f, a3 = 0.f;
#pragma unroll
    for (int i = 0; i < 3; ++i) {
        const int d0 = (lane + 64 * i) * 4;
        const float4 xv = *(const float4*)(xs + d0);
        const float xf[4] = {xv.x, xv.y, xv.z, xv.w};
#pragma unroll
        for (int j = 0; j < 4; ++j) {
            const float4 wq = *(const float4*)(Wm + (size_t)(d0 + j) * 4);
            a0 = fmaf(xf[j], wq.x, a0);
            a1 = fmaf(xf[j], wq.y, a1);
            a2 = fmaf(xf[j], wq.z, a2);
            a3 = fmaf(xf[j], wq.w, a3);
        }
    }

    // ---- visibility of b from 0 ----
    const float* rb = G + ((size_t)batch * S + b) * S;   // slice 0, row b
    const size_t SL = (size_t)8 * S * S;                 // slice stride

    float gb = 0.f, g0 = 0.f;
#pragma unroll
    for (int sl = 0; sl < KQ; ++sl) {
        gb += rb[(size_t)sl * SL + b];
        g0 += rb[(size_t)sl * SL + 0];
    }
    const float denom = (b > 0) ? (float)b : 1.0f;

    bool blocked = false;
    const int nch = (b >> 6) + 1;                        // only chunks with c <= b
    for (int ch = 0; ch < nch; ++ch) {
        const int c = ch * 64 + lane;
        float gc = 0.f;
#pragma unroll
        for (int sl = 0; sl < KQ; ++sl) gc += rb[(size_t)sl * SL + c];
        const float line = gb + ((g0 - gb) * (float)(b - c)) / denom;
        if (c >= 1 && c < b && gc >= line) blocked = true;
    }
    const bool anyb = __any(blocked);

#pragma unroll
    for (int off = 32; off; off >>= 1) {
        a0 += __shfl_xor(a0, off);
        a1 += __shfl_xor(a1, off);
        a2 += __shfl_xor(a2, off);
        a3 += __shfl_xor(a3, off);
    }
    if (lane == 0) {
        float4 o = {a0, a1, a2, a3};
        *(float4*)(P + ((size_t)batch * S + b) * 4) = o;
        wv[batch * S + b] = (b >= 1 && !anyb) ? 1.0f : 0.0f;
    }
}

// logits_k = sum_s w_s * P[s][k]; log_softmax. Grid 8 blocks, wave k per logit.
__global__ __launch_bounds__(256) void head_kernel(const float* __restrict__ P,
                                                   const float* __restrict__ wv,
                                                   float* __restrict__ out) {
    const int batch = blockIdx.x;
    const int k     = threadIdx.x >> 6;
    const int lane  = threadIdx.x & 63;

    float sum = 0.f;
#pragma unroll
    for (int i = 0; i < 4; ++i) {
        const int s = lane + 64 * i;
        sum = fmaf(wv[batch * S + s], P[((size_t)batch * S + s) * 4 + k], sum);
    }
#pragma unroll
    for (int off = 32; off; off >>= 1) sum += __shfl_xor(sum, off);

    __shared__ float lsh[4];
    if (lane == 0) lsh[k] = sum;
    __syncthreads();

    if (threadIdx.x == 0) {
        const float l0 = lsh[0], l1 = lsh[1], l2 = lsh[2], l3 = lsh[3];
        const float m = fmaxf(fmaxf(l0, l1), fmaxf(l2, l3));
        const float lse = logf(expf(l0 - m) + expf(l1 - m) + expf(l2 - m) + expf(l3 - m));
        out[batch * 4 + 0] = l0 - m - lse;
        out[batch * 4 + 1] = l1 - m - lse;
        out[batch * 4 + 2] = l2 - m - lse;
        out[batch * 4 + 3] = l3 - m - lse;
    }
}

extern "C" void kernel_launch(void* const* d_in, const int* in_sizes, int n_in,
                              void* d_out, int out_size, void* d_ws, size_t ws_size,
                              hipStream_t stream) {
    const float* X  = (const float*)d_in[0];   // [8, 256, 768] fp32
    const float* Wm = (const float*)d_in[1];   // [768, 4] fp32
    float* out = (float*)d_out;                // [8, 4] fp32

    float* ws = (float*)d_ws;
    float* P  = ws;                            // 8*256*4 floats
    float* wv = ws + 8192;                     // 8*256 floats
    float* G  = ws + 8192 + 2048;              // 8 slices x 8 x 256 x 256 floats (~16.8 MB)

    gram_kernel <<<dim3(4, 8, 8), 256, 0, stream>>>(X, G);
    visxw_kernel<<<dim3(64, 8),   256, 0, stream>>>(X, Wm, G, P, wv);
    head_kernel <<<8,             256, 0, stream>>>(P, wv, out);
}

// Round 5
// 26.037 us; speedup vs baseline: 1.2030x; 1.2030x over previous
//
#include <hip/hip_runtime.h>
#include <hip/hip_bf16.h>

constexpr int S  = 256;
constexpr int D  = 768;
constexpr int KQ = 8;          // K slices
constexpr int KS = D / KQ;     // 96
constexpr int NT = KS / 16;    // 6 k-tiles of 16

// Lower-triangle 64x64 tile positions (ti >= tj) of the 4x4 tile grid.
__device__ const int TI_MAP[10] = {0,1,1,2,2,2,3,3,3,3};
__device__ const int TJ_MAP[10] = {0,0,1,0,1,2,0,1,2,3};

// Stage 1: per-batch Gram slices G_kq = X[:,kq*96:+96] @ X^T, fp32, TRIANGLE ONLY.
// Grid (10, 8, 8): x = triangle tile pair, y = batch, z = kq. 640 blocks, 256 thr.
// Round-3-proven inner structure: 4x4 micro-tile, [k][row] LDS, 2 ds_read_b128
// per kk feeding 16 FMAs, register prefetch of next k-tile.
// Each slice is bitwise symmetric (fixed k order; fmaf(a,b,c)==fmaf(b,a,c)), so
// off-diagonal tiles are stored twice: normal + transposed (float4-coalesced).
__global__ __launch_bounds__(256) void gram_kernel(const float* __restrict__ X,
                                                   float* __restrict__ G) {
    const int pair  = blockIdx.x;
    const int batch = blockIdx.y;
    const int kq    = blockIdx.z;
    const int tI    = TI_MAP[pair] * 64;
    const int tJ    = TJ_MAP[pair] * 64;
    const int k_base = kq * KS;
    const float* Xb = X + (size_t)batch * S * D;
    float* Gb = G + ((size_t)kq * 8 + batch) * S * S;

    __shared__ float As[16][68];   // [k][row]; fragment reads are ds_read_b128
    __shared__ float Bs[16][68];

    const int t    = threadIdx.x;
    const int tx   = t & 15;       // micro-tile col group
    const int ty   = t >> 4;       // micro-tile row group
    const int srow = t >> 2;       // staging row 0..63
    const int skq  = (t & 3) * 4;  // staging k offset 0,4,8,12 (float4)

    const float* pa = Xb + (size_t)(tI + srow) * D + k_base + skq;
    const float* pb = Xb + (size_t)(tJ + srow) * D + k_base + skq;

    float4 va = *(const float4*)pa;
    float4 vb = *(const float4*)pb;

    float acc[4][4] = {};

    for (int kt = 0; kt < NT; ++kt) {
        __syncthreads();           // previous compute done before overwrite
        As[skq + 0][srow] = va.x; As[skq + 1][srow] = va.y;
        As[skq + 2][srow] = va.z; As[skq + 3][srow] = va.w;
        Bs[skq + 0][srow] = vb.x; Bs[skq + 1][srow] = vb.y;
        Bs[skq + 2][srow] = vb.z; Bs[skq + 3][srow] = vb.w;
        if (kt + 1 < NT) {         // prefetch next tile; latency hides under FMAs
            const int ko = (kt + 1) * 16;
            va = *(const float4*)(pa + ko);
            vb = *(const float4*)(pb + ko);
        }
        __syncthreads();
#pragma unroll
        for (int kk = 0; kk < 16; ++kk) {
            const float4 av = *(const float4*)&As[kk][ty * 4];
            const float4 bv = *(const float4*)&Bs[kk][tx * 4];
            const float a[4] = {av.x, av.y, av.z, av.w};
            const float b[4] = {bv.x, bv.y, bv.z, bv.w};
#pragma unroll
            for (int i = 0; i < 4; ++i)
#pragma unroll
                for (int j = 0; j < 4; ++j)
                    acc[i][j] = fmaf(a[i], b[j], acc[i][j]);
        }
    }

    // Normal store: rows tI+ty*4+i, cols tJ+tx*4+j.
#pragma unroll
    for (int i = 0; i < 4; ++i)
#pragma unroll
        for (int j = 0; j < 4; ++j)
            Gb[(size_t)(tI + ty * 4 + i) * S + (tJ + tx * 4 + j)] = acc[i][j];

    // Mirror store for off-diagonal tiles (bitwise-identical values): rows
    // tJ+tx*4+j get 4 consecutive cols tI+ty*4.. -> coalesced float4 stores.
    if (tI != tJ) {
#pragma unroll
        for (int j = 0; j < 4; ++j) {
            float4 v = make_float4(acc[0][j], acc[1][j], acc[2][j], acc[3][j]);
            *(float4*)(Gb + (size_t)(tJ + tx * 4 + j) * S + tI + ty * 4) = v;
        }
    }
}

// Stage 2 (fused): wave handles position b = blockIdx.x*4 + wave:
//   P[b][:] = x_b @ W; w[b] = visibility of node b from node 0.
// Triangle reads with WAVE-UNIFORM chunk skip (b uniform per wave -> no divergence).
__global__ __launch_bounds__(256) void visxw_kernel(const float* __restrict__ X,
                                                    const float* __restrict__ Wm,
                                                    const float* __restrict__ G,
                                                    float* __restrict__ P,
                                                    float* __restrict__ wv) {
    const int batch = blockIdx.y;
    const int wave  = threadIdx.x >> 6;
    const int lane  = threadIdx.x & 63;
    const int b     = blockIdx.x * 4 + wave;

    // ---- P[b][:] = x_b @ W ----
    const float* xs = X + ((size_t)batch * S + b) * D;
    float a0 = 0.f, a1 = 0.f, a2 = 0.f, a3 = 0.f;
#pragma unroll
    for (int i = 0; i < 3; ++i) {
        const int d0 = (lane + 64 * i) * 4;
        const float4 xv = *(const float4*)(xs + d0);
        const float xf[4] = {xv.x, xv.y, xv.z, xv.w};
#pragma unroll
        for (int j = 0; j < 4; ++j) {
            const float4 wq = *(const float4*)(Wm + (size_t)(d0 + j) * 4);
            a0 = fmaf(xf[j], wq.x, a0);
            a1 = fmaf(xf[j], wq.y, a1);
            a2 = fmaf(xf[j], wq.z, a2);
            a3 = fmaf(xf[j], wq.w, a3);
        }
    }

    // ---- visibility of b from 0 (row b of G == column b bitwise) ----
    const float* rb = G + ((size_t)batch * S + b) * S;
    const size_t SL = (size_t)8 * S * S;   // slice stride

    float gb = 0.f, g0 = 0.f;
#pragma unroll
    for (int sl = 0; sl < KQ; ++sl) {
        gb += rb[(size_t)sl * SL + b];
        g0 += rb[(size_t)sl * SL + 0];
    }
    const float denom = (b > 0) ? (float)b : 1.0f;

    bool blocked = false;
#pragma unroll
    for (int ch = 0; ch < 4; ++ch) {
        if (ch * 64 < b) {                 // wave-uniform branch
            const int c = ch * 64 + lane;
            float gc = 0.f;
#pragma unroll
            for (int sl = 0; sl < KQ; ++sl) gc += rb[(size_t)sl * SL + c];
            const float line = gb + ((g0 - gb) * (float)(b - c)) / denom;
            if (c >= 1 && c < b && gc >= line) blocked = true;
        }
    }
    const bool anyb = __any(blocked);

#pragma unroll
    for (int off = 32; off; off >>= 1) {
        a0 += __shfl_xor(a0, off);
        a1 += __shfl_xor(a1, off);
        a2 += __shfl_xor(a2, off);
        a3 += __shfl_xor(a3, off);
    }
    if (lane == 0) {
        float4 o = {a0, a1, a2, a3};
        *(float4*)(P + ((size_t)batch * S + b) * 4) = o;
        wv[batch * S + b] = (b >= 1 && !anyb) ? 1.0f : 0.0f;
    }
}

// logits_k = sum_s w_s * P[s][k]; log_softmax. Grid 8 blocks, wave k per logit.
__global__ __launch_bounds__(256) void head_kernel(const float* __restrict__ P,
                                                   const float* __restrict__ wv,
                                                   float* __restrict__ out) {
    const int batch = blockIdx.x;
    const int k     = threadIdx.x >> 6;
    const int lane  = threadIdx.x & 63;

    float sum = 0.f;
#pragma unroll
    for (int i = 0; i < 4; ++i) {
        const int s = lane + 64 * i;
        sum = fmaf(wv[batch * S + s], P[((size_t)batch * S + s) * 4 + k], sum);
    }
#pragma unroll
    for (int off = 32; off; off >>= 1) sum += __shfl_xor(sum, off);

    __shared__ float lsh[4];
    if (lane == 0) lsh[k] = sum;
    __syncthreads();

    if (threadIdx.x == 0) {
        const float l0 = lsh[0], l1 = lsh[1], l2 = lsh[2], l3 = lsh[3];
        const float m = fmaxf(fmaxf(l0, l1), fmaxf(l2, l3));
        const float lse = logf(expf(l0 - m) + expf(l1 - m) + expf(l2 - m) + expf(l3 - m));
        out[batch * 4 + 0] = l0 - m - lse;
        out[batch * 4 + 1] = l1 - m - lse;
        out[batch * 4 + 2] = l2 - m - lse;
        out[batch * 4 + 3] = l3 - m - lse;
    }
}

extern "C" void kernel_launch(void* const* d_in, const int* in_sizes, int n_in,
                              void* d_out, int out_size, void* d_ws, size_t ws_size,
                              hipStream_t stream) {
    const float* X  = (const float*)d_in[0];   // [8, 256, 768] fp32
    const float* Wm = (const float*)d_in[1];   // [768, 4] fp32
    float* out = (float*)d_out;                // [8, 4] fp32

    float* ws = (float*)d_ws;
    float* P  = ws;                            // 8*256*4 floats
    float* wv = ws + 8192;                     // 8*256 floats
    float* G  = ws + 8192 + 2048;              // 8 slices x 8 x 256 x 256 floats (~16.8 MB)

    gram_kernel <<<dim3(10, 8, 8), 256, 0, stream>>>(X, G);
    visxw_kernel<<<dim3(64, 8),    256, 0, stream>>>(X, Wm, G, P, wv);
    head_kernel <<<8,              256, 0, stream>>>(P, wv, out);
}